// Round 5
// baseline (632.842 us; speedup 1.0000x reference)
//
#include <hip/hip_runtime.h>

#define S    4096
#define DM   1024
#define H    16
#define DK   64

typedef __bf16 bf16;
typedef __bf16 bf16x8 __attribute__((ext_vector_type(8)));
typedef float  f32x4  __attribute__((ext_vector_type(4)));

// ---------------------------------------------------------------------------
// GEMM: C(4096xDM) = A(4096xDM) @ W^T(DMxDM). A, W fp32 in HBM; staged to
// bf16 in LDS; fp32 MFMA accumulate. 64x64 tile, 4 waves 2x2, 16x16x32 MFMA.
// mode = base_mode + blockIdx.z:
//   0: Q  -> fused RoPE, *0.125, store bf16 [h][s][d]  (ob)
//   1: K  -> fused RoPE,          store bf16 [h][s][d]  (ob)
//   2: V  ->                store bf16 transposed [h][d][s]  (ob)
//   3: out->                store fp32 [m][n] to d_out  (of)
// ---------------------------------------------------------------------------
__global__ __launch_bounds__(256)
void gemm_kernel(const float* __restrict__ A,
                 const float* __restrict__ w0, const float* __restrict__ w1,
                 const float* __restrict__ w2,
                 const int* __restrict__ pos,
                 bf16* __restrict__ o0, bf16* __restrict__ o1,
                 bf16* __restrict__ o2,
                 float* __restrict__ of,
                 int base_mode)
{
    const int z    = blockIdx.z;
    const int mode = base_mode + z;
    const float* W = (z == 0) ? w0 : (z == 1 ? w1 : w2);
    bf16* Out      = (z == 0) ? o0 : (z == 1 ? o1 : o2);

    __shared__ bf16 As[64 * 32];
    __shared__ bf16 Bs[64 * 32];

    const int tid  = threadIdx.x;
    const int lane = tid & 63;
    const int wv   = tid >> 6;
    const int quad = lane >> 4;
    const int col  = lane & 15;
    const int wm   = wv >> 1, wn = wv & 1;

    const int tileM = blockIdx.x * 64;
    const int tileN = blockIdx.y * 64;

    const int ldRow = tid >> 2;        // 0..63
    const int ldK   = (tid & 3) * 8;   // 0,8,16,24 (elements)

    f32x4 acc[2][2] = {};

    for (int kc = 0; kc < DM; kc += 32) {
        f32x4 a_lo = *(const f32x4*)&A[(size_t)(tileM + ldRow) * DM + kc + ldK];
        f32x4 a_hi = *(const f32x4*)&A[(size_t)(tileM + ldRow) * DM + kc + ldK + 4];
        f32x4 b_lo = *(const f32x4*)&W[(size_t)(tileN + ldRow) * DM + kc + ldK];
        f32x4 b_hi = *(const f32x4*)&W[(size_t)(tileN + ldRow) * DM + kc + ldK + 4];
        bf16x8 av, bv;
        for (int j = 0; j < 4; j++) {
            av[j]     = (bf16)a_lo[j];
            av[j + 4] = (bf16)a_hi[j];
            bv[j]     = (bf16)b_lo[j];
            bv[j + 4] = (bf16)b_hi[j];
        }
        __syncthreads();                       // prior-iter LDS reads done
        *(bf16x8*)&As[ldRow * 32 + ldK] = av;
        *(bf16x8*)&Bs[ldRow * 32 + ldK] = bv;
        __syncthreads();

        bf16x8 a0 = *(const bf16x8*)&As[(wm * 32 + 0 * 16 + col) * 32 + quad * 8];
        bf16x8 a1 = *(const bf16x8*)&As[(wm * 32 + 1 * 16 + col) * 32 + quad * 8];
        bf16x8 b0 = *(const bf16x8*)&Bs[(wn * 32 + 0 * 16 + col) * 32 + quad * 8];
        bf16x8 b1 = *(const bf16x8*)&Bs[(wn * 32 + 1 * 16 + col) * 32 + quad * 8];

        acc[0][0] = __builtin_amdgcn_mfma_f32_16x16x32_bf16(a0, b0, acc[0][0], 0, 0, 0);
        acc[0][1] = __builtin_amdgcn_mfma_f32_16x16x32_bf16(a0, b1, acc[0][1], 0, 0, 0);
        acc[1][0] = __builtin_amdgcn_mfma_f32_16x16x32_bf16(a1, b0, acc[1][0], 0, 0, 0);
        acc[1][1] = __builtin_amdgcn_mfma_f32_16x16x32_bf16(a1, b1, acc[1][1], 0, 0, 0);
    }

    // Epilogue. C/D layout: col = lane&15, row = quad*4 + r  [m89/m91]
    for (int fm = 0; fm < 2; fm++)
    for (int fn = 0; fn < 2; fn++) {
        f32x4 v = acc[fm][fn];
        const int n = tileN + wn * 32 + fn * 16 + col;
        for (int r = 0; r < 4; r++) {
            const int m = tileM + wm * 32 + fm * 16 + quad * 4 + r;
            float val = v[r];
            if (mode <= 1) {
                // RoPE: pairs (2i, 2i+1); partner value lives in lane^1
                float part = __shfl_xor(val, 1);
                const int d = n & 63;
                const int i = d >> 1;
                // theta^(-i/32) = 2^(-i * log2(1e4)/32)
                float inv = exp2f(-(float)i * 0.41524101186092034f);
                float ang = (float)pos[m] * inv;
                float c = cosf(ang), sn = sinf(ang);
                float rot = (n & 1) ? (val * c + part * sn)   // odd:  x1*sin + x2*cos
                                    : (val * c - part * sn);  // even: x1*cos - x2*sin
                if (mode == 0) rot *= 0.125f;                 // 1/sqrt(DK), exact
                Out[((size_t)(n >> 6) * S + m) * 64 + d] = (bf16)rot;
            } else if (mode == 2) {
                Out[(size_t)n * S + m] = (bf16)val;           // V^T [h][d][s]
            } else {
                of[(size_t)m * DM + n] = val;                 // d_out is FP32
            }
        }
    }
}

// ---------------------------------------------------------------------------
// Flash attention (causal), transposed scores: St = K.Q^T so softmax state is
// per-lane (col = query). One block = 64 q rows (4 waves x 16), grid (64, H).
// q,k: [h][s][d] bf16 (q pre-scaled); vt: [h][d][s] bf16. ao: [s][DM] fp32.
// ---------------------------------------------------------------------------
__global__ __launch_bounds__(256)
void attn_kernel(const bf16* __restrict__ q, const bf16* __restrict__ k,
                 const bf16* __restrict__ vt, float* __restrict__ ao)
{
    const int qb_  = blockIdx.x;   // 0..63
    const int h    = blockIdx.y;
    const int tid  = threadIdx.x;
    const int lane = tid & 63;
    const int wv   = tid >> 6;
    const int quad = lane >> 4;
    const int col  = lane & 15;

    __shared__ bf16 plds[4][16 * 72];   // per-wave P tile [q=16][key=64(+pad)]

    const int qbase = qb_ * 64 + wv * 16;

    // Q as B-operand fragments: B[n=q=col][kdim=d]
    bf16x8 qf0 = *(const bf16x8*)&q[((size_t)(h * S + qbase + col)) * 64 + 0 * 32 + quad * 8];
    bf16x8 qf1 = *(const bf16x8*)&q[((size_t)(h * S + qbase + col)) * 64 + 1 * 32 + quad * 8];

    float mi = -1e30f, li = 0.f;
    f32x4 o[4] = {};

    const int gq = qbase + col;

    for (int kt = 0; kt <= qb_; kt++) {
        const int kbase = kt * 64;

        // St tile: 64 keys x 16 q  (4 key-groups of 16)
        f32x4 st[4];
        for (int kg = 0; kg < 4; kg++) {
            const bf16* kp = &k[((size_t)(h * S + kbase + kg * 16 + col)) * 64 + quad * 8];
            bf16x8 kf0 = *(const bf16x8*)kp;
            bf16x8 kf1 = *(const bf16x8*)(kp + 32);
            f32x4 z = {};
            z = __builtin_amdgcn_mfma_f32_16x16x32_bf16(kf0, qf0, z, 0, 0, 0);
            z = __builtin_amdgcn_mfma_f32_16x16x32_bf16(kf1, qf1, z, 0, 0, 0);
            st[kg] = z;
        }

        // causal mask + per-lane partial max over this lane's 16 keys
        float mt = -1e30f;
        for (int kg = 0; kg < 4; kg++)
            for (int r = 0; r < 4; r++) {
                const int gk = kbase + kg * 16 + quad * 4 + r;
                float s = st[kg][r];
                s = (gk > gq) ? -1e30f : s;
                st[kg][r] = s;
                mt = fmaxf(mt, s);
            }
        // combine the 4 quads (same col == same query)
        mt = fmaxf(mt, __shfl_xor(mt, 16));
        mt = fmaxf(mt, __shfl_xor(mt, 32));

        const float mnew  = fmaxf(mi, mt);
        const float alpha = __expf(mi - mnew);

        float ps = 0.f;
        for (int kg = 0; kg < 4; kg++)
            for (int r = 0; r < 4; r++) {
                float p = __expf(st[kg][r] - mnew);
                ps += p;
                plds[wv][col * 72 + kg * 16 + quad * 4 + r] = (bf16)p;
            }
        ps += __shfl_xor(ps, 16);
        ps += __shfl_xor(ps, 32);

        li = li * alpha + ps;
        mi = mnew;
        for (int dg = 0; dg < 4; dg++)
            for (int r = 0; r < 4; r++) o[dg][r] *= alpha;

        __builtin_amdgcn_wave_barrier();   // keep P writes before P reads

        // P as B-operand: B[n=q=col][kdim=key]
        bf16x8 pb0 = *(const bf16x8*)&plds[wv][col * 72 + 0 * 32 + quad * 8];
        bf16x8 pb1 = *(const bf16x8*)&plds[wv][col * 72 + 1 * 32 + quad * 8];

        // O^T[d][q] += V^T[d][key] * P^T[key][q]
        for (int dg = 0; dg < 4; dg++) {
            const bf16* vp = &vt[((size_t)(h * 64 + dg * 16 + col)) * S + kbase + quad * 8];
            bf16x8 va0 = *(const bf16x8*)vp;
            bf16x8 va1 = *(const bf16x8*)(vp + 32);
            o[dg] = __builtin_amdgcn_mfma_f32_16x16x32_bf16(va0, pb0, o[dg], 0, 0, 0);
            o[dg] = __builtin_amdgcn_mfma_f32_16x16x32_bf16(va1, pb1, o[dg], 0, 0, 0);
        }
    }

    const float rli = 1.f / li;
    for (int dg = 0; dg < 4; dg++) {
        f32x4 ov;
        for (int r = 0; r < 4; r++) ov[r] = o[dg][r] * rli;
        // O^T: row = d = dg*16 + quad*4 + r, col = q  -> ao[s][h*64+d]
        *(f32x4*)&ao[(size_t)(qbase + col) * DM + h * 64 + dg * 16 + quad * 4] = ov;
    }
}

// ---------------------------------------------------------------------------
extern "C" void kernel_launch(void* const* d_in, const int* in_sizes, int n_in,
                              void* d_out, int out_size, void* d_ws, size_t ws_size,
                              hipStream_t stream)
{
    const float* x   = (const float*)d_in[0];
    const int*   pos = (const int*)d_in[1];
    const float* Wq  = (const float*)d_in[2];
    const float* Wk  = (const float*)d_in[3];
    const float* Wv  = (const float*)d_in[4];
    const float* Wo  = (const float*)d_in[5];
    float* out = (float*)d_out;   // reference output dtype is float32

    // workspace layout (40 MB):
    //   [0, 8M)   qb bf16 [h][s][d]
    //   [8,16M)   kb bf16 [h][s][d]
    //   [16,24M)  vt bf16 [h][d][s]
    //   [24,40M)  ao fp32 [s][DM]
    char* w = (char*)d_ws;
    bf16*  qb  = (bf16*)(w);
    bf16*  kb  = (bf16*)(w + (size_t)8  * 1024 * 1024);
    bf16*  vt  = (bf16*)(w + (size_t)16 * 1024 * 1024);
    float* aof = (float*)(w + (size_t)24 * 1024 * 1024);

    dim3 blk(256);
    gemm_kernel<<<dim3(64, 16, 3), blk, 0, stream>>>(x, Wq, Wk, Wv, pos,
                                                     qb, kb, vt, out, 0);
    attn_kernel<<<dim3(64, 16), blk, 0, stream>>>(qb, kb, vt, aof);
    gemm_kernel<<<dim3(64, 16, 1), blk, 0, stream>>>(aof, Wo, Wo, Wo, pos,
                                                     qb, kb, vt, out, 3);
}

// Round 6
// 312.370 us; speedup vs baseline: 2.0259x; 2.0259x over previous
//
#include <hip/hip_runtime.h>

#define S    4096
#define DM   1024
#define H    16
#define DK   64

typedef __bf16 bf16;
typedef __bf16 bf16x8 __attribute__((ext_vector_type(8)));
typedef float  f32x4  __attribute__((ext_vector_type(4)));

// ---------------------------------------------------------------------------
// GEMM: C(4096xDM) = A(4096xDM) @ W^T(DMxDM). A, W fp32 in HBM; staged to
// bf16 in LDS; fp32 MFMA accumulate. 64x64 tile, 4 waves 2x2, 16x16x32 MFMA.
// mode = base_mode + blockIdx.z:
//   0: Q  -> fused RoPE, *0.125, store bf16 [h][s][d]  (ob)
//   1: K  -> fused RoPE,          store bf16 [h][s][d]  (ob)
//   2: V  ->                store bf16 transposed [h][d][s]  (ob)
//   3: out->                store fp32 [m][n] to d_out  (of)
// ---------------------------------------------------------------------------
__global__ __launch_bounds__(256)
void gemm_kernel(const float* __restrict__ A,
                 const float* __restrict__ w0, const float* __restrict__ w1,
                 const float* __restrict__ w2,
                 const int* __restrict__ pos,
                 bf16* __restrict__ o0, bf16* __restrict__ o1,
                 bf16* __restrict__ o2,
                 float* __restrict__ of,
                 int base_mode)
{
    const int z    = blockIdx.z;
    const int mode = base_mode + z;
    const float* W = (z == 0) ? w0 : (z == 1 ? w1 : w2);
    bf16* Out      = (z == 0) ? o0 : (z == 1 ? o1 : o2);

    __shared__ bf16 As[64 * 32];
    __shared__ bf16 Bs[64 * 32];

    const int tid  = threadIdx.x;
    const int lane = tid & 63;
    const int wv   = tid >> 6;
    const int quad = lane >> 4;
    const int col  = lane & 15;
    const int wm   = wv >> 1, wn = wv & 1;

    const int tileM = blockIdx.x * 64;
    const int tileN = blockIdx.y * 64;

    const int ldRow = tid >> 2;        // 0..63
    const int ldK   = (tid & 3) * 8;   // 0,8,16,24 (elements)

    f32x4 acc[2][2] = {};

    for (int kc = 0; kc < DM; kc += 32) {
        f32x4 a_lo = *(const f32x4*)&A[(size_t)(tileM + ldRow) * DM + kc + ldK];
        f32x4 a_hi = *(const f32x4*)&A[(size_t)(tileM + ldRow) * DM + kc + ldK + 4];
        f32x4 b_lo = *(const f32x4*)&W[(size_t)(tileN + ldRow) * DM + kc + ldK];
        f32x4 b_hi = *(const f32x4*)&W[(size_t)(tileN + ldRow) * DM + kc + ldK + 4];
        bf16x8 av, bv;
        for (int j = 0; j < 4; j++) {
            av[j]     = (bf16)a_lo[j];
            av[j + 4] = (bf16)a_hi[j];
            bv[j]     = (bf16)b_lo[j];
            bv[j + 4] = (bf16)b_hi[j];
        }
        __syncthreads();                       // prior-iter LDS reads done
        *(bf16x8*)&As[ldRow * 32 + ldK] = av;
        *(bf16x8*)&Bs[ldRow * 32 + ldK] = bv;
        __syncthreads();

        bf16x8 a0 = *(const bf16x8*)&As[(wm * 32 + 0 * 16 + col) * 32 + quad * 8];
        bf16x8 a1 = *(const bf16x8*)&As[(wm * 32 + 1 * 16 + col) * 32 + quad * 8];
        bf16x8 b0 = *(const bf16x8*)&Bs[(wn * 32 + 0 * 16 + col) * 32 + quad * 8];
        bf16x8 b1 = *(const bf16x8*)&Bs[(wn * 32 + 1 * 16 + col) * 32 + quad * 8];

        acc[0][0] = __builtin_amdgcn_mfma_f32_16x16x32_bf16(a0, b0, acc[0][0], 0, 0, 0);
        acc[0][1] = __builtin_amdgcn_mfma_f32_16x16x32_bf16(a0, b1, acc[0][1], 0, 0, 0);
        acc[1][0] = __builtin_amdgcn_mfma_f32_16x16x32_bf16(a1, b0, acc[1][0], 0, 0, 0);
        acc[1][1] = __builtin_amdgcn_mfma_f32_16x16x32_bf16(a1, b1, acc[1][1], 0, 0, 0);
    }

    // Epilogue. C/D layout: col = lane&15, row = quad*4 + r  [m89/m91]
    for (int fm = 0; fm < 2; fm++)
    for (int fn = 0; fn < 2; fn++) {
        f32x4 v = acc[fm][fn];
        const int n = tileN + wn * 32 + fn * 16 + col;
        for (int r = 0; r < 4; r++) {
            const int m = tileM + wm * 32 + fm * 16 + quad * 4 + r;
            float val = v[r];
            if (mode <= 1) {
                // RoPE: pairs (2i, 2i+1); partner value lives in lane^1
                float part = __shfl_xor(val, 1);
                const int d = n & 63;
                const int i = d >> 1;
                float inv = exp2f(-(float)i * 0.41524101186092034f); // 1e4^(-i/32)
                float ang = (float)pos[m] * inv;
                float c = cosf(ang), sn = sinf(ang);
                float rot = (n & 1) ? (val * c + part * sn)
                                    : (val * c - part * sn);
                if (mode == 0) rot *= 0.125f;                 // 1/sqrt(DK)
                Out[((size_t)(n >> 6) * S + m) * 64 + d] = (bf16)rot;
            } else if (mode == 2) {
                Out[(size_t)n * S + m] = (bf16)val;           // V^T [h][d][s]
            } else {
                of[(size_t)m * DM + n] = val;                 // d_out fp32
            }
        }
    }
}

// ---------------------------------------------------------------------------
// Flash attention (causal), transposed scores: St = K.Q^T, col = query.
// Block = 4 waves x 16 q = 64 queries; grid (64, H).
// K-tile and V^T-tile staged cooperatively in LDS (pad 72 -> 2-way max,
// free per m136), shared by all 4 waves: 4x less global traffic than R5.
// q,k: [h][s][d] bf16 (q pre-scaled); vt: [h][d][s] bf16. ao: [s][DM] fp32.
// ---------------------------------------------------------------------------
__global__ __launch_bounds__(256, 3)
void attn_kernel(const bf16* __restrict__ q, const bf16* __restrict__ k,
                 const bf16* __restrict__ vt, float* __restrict__ ao)
{
    const int qb_  = blockIdx.x;   // 0..63
    const int h    = blockIdx.y;
    const int tid  = threadIdx.x;
    const int lane = tid & 63;
    const int wv   = tid >> 6;
    const int quad = lane >> 4;
    const int col  = lane & 15;

    __shared__ bf16 Ks[64 * 72];        // K[key][d],  padded
    __shared__ bf16 Vs[64 * 72];        // V^T[d][key], padded
    __shared__ bf16 plds[4][16 * 72];   // per-wave P tile [q][key], padded

    const int qbase = qb_ * 64 + wv * 16;

    // Q as B-operand fragments: B[n=q=col][kdim=d]
    bf16x8 qf0 = *(const bf16x8*)&q[((size_t)(h * S + qbase + col)) * 64 + quad * 8];
    bf16x8 qf1 = *(const bf16x8*)&q[((size_t)(h * S + qbase + col)) * 64 + 32 + quad * 8];

    float mi = -1e30f, li = 0.f;
    f32x4 o[4] = {};
    const int gq = qbase + col;

    // staging pattern: thread t -> row t>>2, 16-elem segment (t&3)*16
    const int srow = tid >> 2;
    const int sseg = (tid & 3) * 16;
    const bf16* kg_ = k  + ((size_t)h * S) * 64;
    const bf16* vg_ = vt + ((size_t)h * 64) * S;

    for (int kt = 0; kt <= qb_; kt++) {
        const int kbase = kt * 64;

        // prefetch tile into regs (before the barrier)
        const bf16* kp = kg_ + (size_t)(kbase + srow) * 64 + sseg;  // K tile: contiguous 8KB
        const bf16* vp = vg_ + (size_t)srow * S + kbase + sseg;     // V^T rows, stride S
        bf16x8 kr0 = *(const bf16x8*)kp;
        bf16x8 kr1 = *(const bf16x8*)(kp + 8);
        bf16x8 vr0 = *(const bf16x8*)vp;
        bf16x8 vr1 = *(const bf16x8*)(vp + 8);

        __syncthreads();                 // prior-iter LDS fragment reads done
        *(bf16x8*)&Ks[srow * 72 + sseg]     = kr0;
        *(bf16x8*)&Ks[srow * 72 + sseg + 8] = kr1;
        *(bf16x8*)&Vs[srow * 72 + sseg]     = vr0;
        *(bf16x8*)&Vs[srow * 72 + sseg + 8] = vr1;
        __syncthreads();

        // St tile: 64 keys x 16 q (A = K from LDS)
        f32x4 st[4];
        for (int kg = 0; kg < 4; kg++) {
            bf16x8 kf0 = *(const bf16x8*)&Ks[(kg * 16 + col) * 72 + quad * 8];
            bf16x8 kf1 = *(const bf16x8*)&Ks[(kg * 16 + col) * 72 + 32 + quad * 8];
            f32x4 z = {};
            z = __builtin_amdgcn_mfma_f32_16x16x32_bf16(kf0, qf0, z, 0, 0, 0);
            z = __builtin_amdgcn_mfma_f32_16x16x32_bf16(kf1, qf1, z, 0, 0, 0);
            st[kg] = z;
        }

        // causal mask only on the diagonal tile (block-uniform branch)
        float mt = -1e30f;
        if (kt == qb_) {
            for (int kg = 0; kg < 4; kg++)
                for (int r = 0; r < 4; r++) {
                    const int gk = kbase + kg * 16 + quad * 4 + r;
                    float s = st[kg][r];
                    s = (gk > gq) ? -1e30f : s;
                    st[kg][r] = s;
                    mt = fmaxf(mt, s);
                }
        } else {
            for (int kg = 0; kg < 4; kg++)
                for (int r = 0; r < 4; r++)
                    mt = fmaxf(mt, st[kg][r]);
        }
        mt = fmaxf(mt, __shfl_xor(mt, 16));
        mt = fmaxf(mt, __shfl_xor(mt, 32));

        const float mnew  = fmaxf(mi, mt);
        const float alpha = __expf(mi - mnew);

        float ps = 0.f;
        for (int kg = 0; kg < 4; kg++)
            for (int r = 0; r < 4; r++) {
                float p = __expf(st[kg][r] - mnew);
                ps += p;
                plds[wv][col * 72 + kg * 16 + quad * 4 + r] = (bf16)p;
            }
        ps += __shfl_xor(ps, 16);
        ps += __shfl_xor(ps, 32);

        li = li * alpha + ps;
        mi = mnew;
        for (int dg = 0; dg < 4; dg++)
            for (int r = 0; r < 4; r++) o[dg][r] *= alpha;

        __builtin_amdgcn_wave_barrier();   // keep P writes before P reads

        // P as B-operand: B[n=q=col][kdim=key]
        bf16x8 pb0 = *(const bf16x8*)&plds[wv][col * 72 + quad * 8];
        bf16x8 pb1 = *(const bf16x8*)&plds[wv][col * 72 + 32 + quad * 8];

        // O^T[d][q] += V^T[d][key] * P^T[key][q]  (A = V^T from LDS)
        for (int dg = 0; dg < 4; dg++) {
            bf16x8 va0 = *(const bf16x8*)&Vs[(dg * 16 + col) * 72 + quad * 8];
            bf16x8 va1 = *(const bf16x8*)&Vs[(dg * 16 + col) * 72 + 32 + quad * 8];
            o[dg] = __builtin_amdgcn_mfma_f32_16x16x32_bf16(va0, pb0, o[dg], 0, 0, 0);
            o[dg] = __builtin_amdgcn_mfma_f32_16x16x32_bf16(va1, pb1, o[dg], 0, 0, 0);
        }
    }

    const float rli = 1.f / li;
    for (int dg = 0; dg < 4; dg++) {
        f32x4 ov;
        for (int r = 0; r < 4; r++) ov[r] = o[dg][r] * rli;
        // O^T: row = d = dg*16 + quad*4 + r, col = q  -> ao[s][h*64+d]
        *(f32x4*)&ao[(size_t)(qbase + col) * DM + h * 64 + dg * 16 + quad * 4] = ov;
    }
}

// ---------------------------------------------------------------------------
extern "C" void kernel_launch(void* const* d_in, const int* in_sizes, int n_in,
                              void* d_out, int out_size, void* d_ws, size_t ws_size,
                              hipStream_t stream)
{
    const float* x   = (const float*)d_in[0];
    const int*   pos = (const int*)d_in[1];
    const float* Wq  = (const float*)d_in[2];
    const float* Wk  = (const float*)d_in[3];
    const float* Wv  = (const float*)d_in[4];
    const float* Wo  = (const float*)d_in[5];
    float* out = (float*)d_out;   // reference output dtype is float32

    // workspace layout (40 MB):
    //   [0, 8M)   qb bf16 [h][s][d]
    //   [8,16M)   kb bf16 [h][s][d]
    //   [16,24M)  vt bf16 [h][d][s]
    //   [24,40M)  ao fp32 [s][DM]
    char* w = (char*)d_ws;
    bf16*  qb  = (bf16*)(w);
    bf16*  kb  = (bf16*)(w + (size_t)8  * 1024 * 1024);
    bf16*  vt  = (bf16*)(w + (size_t)16 * 1024 * 1024);
    float* aof = (float*)(w + (size_t)24 * 1024 * 1024);

    dim3 blk(256);
    gemm_kernel<<<dim3(64, 16, 3), blk, 0, stream>>>(x, Wq, Wk, Wv, pos,
                                                     qb, kb, vt, out, 0);
    attn_kernel<<<dim3(64, 16), blk, 0, stream>>>(qb, kb, vt, aof);
    gemm_kernel<<<dim3(64, 16, 1), blk, 0, stream>>>(aof, Wo, Wo, Wo, pos,
                                                     qb, kb, vt, out, 3);
}